// Round 1
// baseline (1054.588 us; speedup 1.0000x reference)
//
#include <hip/hip_runtime.h>

typedef unsigned short u16;
typedef u16  u16x8 __attribute__((ext_vector_type(8)));
typedef u16  u16x4 __attribute__((ext_vector_type(4)));
typedef short s16x8 __attribute__((ext_vector_type(8)));
typedef float f32x4 __attribute__((ext_vector_type(4)));

static constexpr int TT   = 2048;   // tokens (B*S)
static constexpr int HD   = 2048;   // hidden
static constexpr int ID   = 1408;   // expert intermediate
static constexpr int NE   = 16;     // experts
static constexpr int TOPK = 6;
static constexpr int CAPE = 1536;   // capacity
static constexpr int SHD  = 2816;   // shared intermediate (2*I)
static constexpr float RSF_ = 2.5f;

__device__ __forceinline__ u16 f2b(float f) {
  unsigned int u = __builtin_bit_cast(unsigned int, f);
  unsigned int r = (u + 0x7FFFu + ((u >> 16) & 1u)) >> 16;
  return (u16)r;
}
__device__ __forceinline__ float b2f(u16 u) {
  unsigned int v = ((unsigned int)u) << 16;
  return __builtin_bit_cast(float, v);
}

// ---------------- x fp32 -> bf16 ----------------
__global__ __launch_bounds__(256) void k_cvt(const float* __restrict__ in, u16* __restrict__ out) {
  size_t i = (size_t)blockIdx.x * 256 + threadIdx.x;
  const float4* p = (const float4*)in;
  float4 v0 = p[i * 2], v1 = p[i * 2 + 1];
  u16x8 o = { f2b(v0.x), f2b(v0.y), f2b(v0.z), f2b(v0.w),
              f2b(v1.x), f2b(v1.y), f2b(v1.z), f2b(v1.w) };
  *(u16x8*)(out + i * 8) = o;
}

// ---------------- gate: logits + noaux_tc group top-k ----------------
__global__ __launch_bounds__(64) void k_gate(const float* __restrict__ x,
    const float* __restrict__ gw, const float* __restrict__ gb,
    int* __restrict__ topk_idx, float* __restrict__ topk_w) {
  const int t = blockIdx.x, l = threadIdx.x;
  const float* xr = x + (size_t)t * HD;
  float logit[NE];
  #pragma unroll
  for (int e = 0; e < NE; ++e) {
    const float* wr = gw + (size_t)e * HD;
    float p = 0.f;
    for (int j = l; j < HD; j += 64) p += xr[j] * wr[j];
    #pragma unroll
    for (int o = 32; o; o >>= 1) p += __shfl_down(p, o);
    logit[e] = p;  // valid on lane 0
  }
  if (l != 0) return;
  float s[NE], sc[NE];
  #pragma unroll
  for (int e = 0; e < NE; ++e) {
    s[e]  = 1.f / (1.f + expf(-logit[e]));   // precise expf: top-k tie robustness
    sc[e] = s[e] + gb[e];
  }
  float gs[4];
  #pragma unroll
  for (int g = 0; g < 4; ++g) {
    float m1 = -1e30f, m2 = -1e30f;
    #pragma unroll
    for (int j = 0; j < 4; ++j) {
      float v = sc[g * 4 + j];
      if (v > m1) { m2 = m1; m1 = v; } else if (v > m2) m2 = v;
    }
    gs[g] = m1 + m2;
  }
  int g0 = 0;
  #pragma unroll
  for (int g = 1; g < 4; ++g) if (gs[g] > gs[g0]) g0 = g;
  int g1 = -1; float g1v = -1e30f;
  #pragma unroll
  for (int g = 0; g < 4; ++g) {
    if (g == g0) continue;
    if (g1 < 0 || gs[g] > g1v) { g1 = g; g1v = gs[g]; }
  }
  float tmp[NE];
  #pragma unroll
  for (int e = 0; e < NE; ++e) {
    int g = e >> 2;
    tmp[e] = (g == g0 || g == g1) ? sc[e] : -1.f;  // masked-in scores are >0
  }
  unsigned used = 0;
  float wsum = 0.f;
  int idxs[TOPK]; float wv[TOPK];
  #pragma unroll
  for (int k = 0; k < TOPK; ++k) {
    int best = -1; float bv = -2e30f;
    #pragma unroll
    for (int e = 0; e < NE; ++e) {
      bool ok = (((used >> e) & 1u) == 0u) && (tmp[e] > bv);
      if (ok) { bv = tmp[e]; best = e; }
    }
    used |= 1u << best;
    float sv = 0.f;
    #pragma unroll
    for (int e = 0; e < NE; ++e) if (e == best) sv = s[e];
    idxs[k] = best; wv[k] = sv; wsum += sv;
  }
  float scale = RSF_ / (wsum + 1e-20f);
  #pragma unroll
  for (int k = 0; k < TOPK; ++k) {
    topk_idx[t * TOPK + k] = idxs[k];
    topk_w[t * TOPK + k]   = wv[k] * scale;
  }
}

// ---------------- stable per-expert positions (matches stable sort) ----------------
__global__ __launch_bounds__(256) void k_count_pos(const int* __restrict__ topk_idx,
    int* __restrict__ rowidx, int* __restrict__ tok_of_row, int* __restrict__ counts) {
  const int e = blockIdx.x, t = threadIdx.x;
  __shared__ int pref[256];
  const int t0 = t * 8;
  int c = 0;
  for (int tt = t0; tt < t0 + 8; ++tt)
    for (int k = 0; k < TOPK; ++k) c += (topk_idx[tt * TOPK + k] == e) ? 1 : 0;
  pref[t] = c;
  __syncthreads();
  for (int off = 1; off < 256; off <<= 1) {
    int v = (t >= off) ? pref[t - off] : 0;
    __syncthreads();
    pref[t] += v;
    __syncthreads();
  }
  int run = pref[t] - c;  // exclusive prefix
  if (t == 255) counts[e] = (pref[255] < CAPE) ? pref[255] : CAPE;
  for (int tt = t0; tt < t0 + 8; ++tt)
    for (int k = 0; k < TOPK; ++k)
      if (topk_idx[tt * TOPK + k] == e) {
        if (run < CAPE) {
          rowidx[tt * TOPK + k] = e * CAPE + run;
          tok_of_row[e * CAPE + run] = tt;
        } else {
          rowidx[tt * TOPK + k] = -1;   // dropped (should not happen)
        }
        ++run;
      }
}

// ---------------- transpose + convert: fp32 [R][C] -> bf16 [C][R] ----------------
__global__ __launch_bounds__(256) void k_transpose_cvt(const float* __restrict__ in,
    u16* __restrict__ out, int R, int Cc, long zin, long zout) {
  __shared__ float tile[64][65];
  const float* src = in + (size_t)blockIdx.z * zin;
  u16* dst = out + (size_t)blockIdx.z * zout;
  const int r0 = blockIdx.x * 64, c0 = blockIdx.y * 64, t = threadIdx.x;
  #pragma unroll
  for (int i = 0; i < 4; ++i) {
    int c = t + 256 * i;
    int r = c >> 4, cg = (c & 15) << 2;
    float4 v = *(const float4*)(src + (size_t)(r0 + r) * Cc + c0 + cg);
    tile[r][cg + 0] = v.x; tile[r][cg + 1] = v.y;
    tile[r][cg + 2] = v.z; tile[r][cg + 3] = v.w;
  }
  __syncthreads();
  #pragma unroll
  for (int i = 0; i < 4; ++i) {
    int c = t + 256 * i;
    int oc = c >> 4, og = (c & 15) << 2;
    u16x4 w;
    #pragma unroll
    for (int j = 0; j < 4; ++j) w[j] = f2b(tile[og + j][oc]);
    *(u16x4*)(dst + (size_t)(c0 + oc) * R + r0 + og) = w;
  }
}

// ---------------- bf16 GEMM: C = A[M][K] * Bt[N][K]^T  (grouped via z) ----------------
// row_map: optional gather map for A rows (indexed row_base + r).
// counts: per-expert M (clamped to row_cap); null -> Mfixed, row_base = 0.
template <bool C_F32>
__global__ __launch_bounds__(256) void k_gemm_bt(
    const u16* __restrict__ A, const u16* __restrict__ Bt, void* __restrict__ Cptr,
    const int* __restrict__ row_map, const int* __restrict__ counts,
    int Mfixed, int N, int K, int lda, int ldc, long bt_stride, int row_cap) {
  const int e = blockIdx.z;
  const int cnt = counts ? counts[e] : Mfixed;
  const int M_e = counts ? (cnt < row_cap ? cnt : row_cap) : Mfixed;
  const int m0 = blockIdx.x * 128;
  if (m0 >= M_e) return;
  const int n0 = blockIdx.y * 128;
  const int row_base = counts ? e * row_cap : 0;
  const u16* Bte = Bt + (size_t)e * bt_stride;

  __shared__ __align__(16) u16 As[128 * 32];
  __shared__ __align__(16) u16 Bs[128 * 32];

  const int t = threadIdx.x;
  const int l = t & 63, w = t >> 6;
  const int wm = (w >> 1) * 64, wn = (w & 1) * 64;

  // staging: 2 A-chunks + 2 B-chunks of 16B per thread per K-step
  const u16* aptr[2]; const u16* bptr[2];
  int lds_off[2];
  #pragma unroll
  for (int i = 0; i < 2; ++i) {
    int c = t + 256 * i;
    int row = c >> 2, kg = c & 3;
    int sw = (row ^ (row >> 2)) & 3;
    lds_off[i] = row * 64 + (((kg ^ sw) & 3) << 4);
    int rg = m0 + row; if (rg > M_e - 1) rg = M_e - 1;
    int arow = row_map ? row_map[row_base + rg] : row_base + rg;
    aptr[i] = A + (size_t)arow * lda + kg * 8;
    bptr[i] = Bte + (size_t)(n0 + row) * K + kg * 8;
  }

  f32x4 acc[4][4];
  #pragma unroll
  for (int m = 0; m < 4; ++m)
    #pragma unroll
    for (int n = 0; n < 4; ++n) acc[m][n] = f32x4{0.f, 0.f, 0.f, 0.f};

  // fragment read offsets (bytes), same swizzle as staging
  int aoff[4], boff[4];
  {
    int l15 = l & 15, g = l >> 4;
    int sw = (l15 ^ (l15 >> 2)) & 3;
    #pragma unroll
    for (int i = 0; i < 4; ++i) {
      int rA = wm + i * 16 + l15;
      int rB = wn + i * 16 + l15;
      aoff[i] = rA * 64 + (((g ^ sw) & 3) << 4);
      boff[i] = rB * 64 + (((g ^ sw) & 3) << 4);
    }
  }

  const int nk = K >> 5;
  for (int ks = 0; ks < nk; ++ks) {
    u16x8 av[2], bv[2];
    #pragma unroll
    for (int i = 0; i < 2; ++i) {
      av[i] = *(const u16x8*)aptr[i]; aptr[i] += 32;
      bv[i] = *(const u16x8*)bptr[i]; bptr[i] += 32;
    }
    __syncthreads();
    #pragma unroll
    for (int i = 0; i < 2; ++i) {
      *(u16x8*)((char*)As + lds_off[i]) = av[i];
      *(u16x8*)((char*)Bs + lds_off[i]) = bv[i];
    }
    __syncthreads();
    s16x8 af[4], bfr[4];
    #pragma unroll
    for (int i = 0; i < 4; ++i) {
      af[i]  = __builtin_bit_cast(s16x8, *(const u16x8*)((const char*)As + aoff[i]));
      bfr[i] = __builtin_bit_cast(s16x8, *(const u16x8*)((const char*)Bs + boff[i]));
    }
    #pragma unroll
    for (int m = 0; m < 4; ++m)
      #pragma unroll
      for (int n = 0; n < 4; ++n)
        acc[m][n] = __builtin_amdgcn_mfma_f32_16x16x32_bf16(af[m], bfr[n], acc[m][n], 0, 0, 0);
  }

  // epilogue: C row = (lane>>4)*4 + j, col = lane&15 within each 16x16 tile
  const int cl = l & 15, rw = (l >> 4) * 4;
  #pragma unroll
  for (int m = 0; m < 4; ++m) {
    #pragma unroll
    for (int n = 0; n < 4; ++n) {
      f32x4 v = acc[m][n];
      int gr0 = m0 + wm + m * 16 + rw;
      int gc  = n0 + wn + n * 16 + cl;
      #pragma unroll
      for (int j = 0; j < 4; ++j) {
        int r = gr0 + j;
        if (r < M_e) {
          size_t ci = (size_t)(row_base + r) * ldc + gc;
          if (C_F32) ((float*)Cptr)[ci] = v[j];
          else       ((u16*)Cptr)[ci]   = f2b(v[j]);
        }
      }
    }
  }
}

// ---------------- silu(g)*u, elementwise, in bf16 (may alias o==g) ----------------
__global__ __launch_bounds__(256) void k_silu_mul(const u16* __restrict__ g,
    const u16* __restrict__ u, u16* __restrict__ o) {
  size_t i = (size_t)blockIdx.x * 256 + threadIdx.x;
  u16x8 gv = *(const u16x8*)(g + i * 8);
  u16x8 uv = *(const u16x8*)(u + i * 8);
  u16x8 ov;
  #pragma unroll
  for (int j = 0; j < 8; ++j) {
    float gf = b2f(gv[j]), uf = b2f(uv[j]);
    float sf = gf / (1.f + __expf(-gf));
    ov[j] = f2b(sf * uf);
  }
  *(u16x8*)(o + i * 8) = ov;
}

// ---------------- combine: out[t] += sum_k w * down[row(t,k)] ----------------
__global__ __launch_bounds__(256) void k_combine(const u16* __restrict__ down,
    const int* __restrict__ rowidx, const float* __restrict__ tw,
    float* __restrict__ out) {
  const int t = blockIdx.x, l = threadIdx.x;
  __shared__ int rid[TOPK];
  __shared__ float wk[TOPK];
  if (l < TOPK) { rid[l] = rowidx[t * TOPK + l]; wk[l] = tw[t * TOPK + l]; }
  __syncthreads();
  const int h0 = l * 8;
  float* op = out + (size_t)t * HD + h0;
  float4 o0 = *(float4*)op, o1 = *(float4*)(op + 4);
  float a[8] = { o0.x, o0.y, o0.z, o0.w, o1.x, o1.y, o1.z, o1.w };
  #pragma unroll
  for (int k = 0; k < TOPK; ++k) {
    int r = rid[k];
    if (r < 0) continue;
    float wkk = wk[k];
    u16x8 v = *(const u16x8*)(down + (size_t)r * HD + h0);
    #pragma unroll
    for (int j = 0; j < 8; ++j) a[j] += wkk * b2f(v[j]);
  }
  o0 = make_float4(a[0], a[1], a[2], a[3]);
  o1 = make_float4(a[4], a[5], a[6], a[7]);
  *(float4*)op = o0;
  *(float4*)(op + 4) = o1;
}

__global__ __launch_bounds__(256) void k_sentinel(float* o, int n) {
  int i = blockIdx.x * 256 + threadIdx.x;
  if (i < n) o[i] = 12345.0f;
}

extern "C" void kernel_launch(void* const* d_in, const int* in_sizes, int n_in,
                              void* d_out, int out_size, void* d_ws, size_t ws_size,
                              hipStream_t stream) {
  const float* x       = (const float*)d_in[0];
  const float* gate_w  = (const float*)d_in[1];
  const float* gate_b  = (const float*)d_in[2];
  const float* w_gate  = (const float*)d_in[3];
  const float* w_up    = (const float*)d_in[4];
  const float* w_down  = (const float*)d_in[5];
  const float* ws_gate = (const float*)d_in[6];
  const float* ws_up   = (const float*)d_in[7];
  const float* ws_down = (const float*)d_in[8];
  float* out = (float*)d_out;

  char* base = (char*)d_ws;
  char* p = base;
  auto alloc = [&](size_t bytes) -> char* {
    char* r = p;
    p += (bytes + 255) & ~(size_t)255;
    return r;
  };
  u16* wT    = (u16*)alloc((size_t)NE * ID * HD * 2);   // routed weight^T (reused x3)
  u16* swT   = (u16*)alloc((size_t)SHD * HD * 2);       // shared weight^T (reused x3)
  u16* xb    = (u16*)alloc((size_t)TT * HD * 2);        // x in bf16
  u16* gbuf  = (u16*)alloc((size_t)NE * CAPE * ID * 2); // g -> act ; later sg
  u16* ubuf  = (u16*)alloc((size_t)NE * CAPE * ID * 2); // u        ; later su
  u16* dbuf  = (u16*)alloc((size_t)NE * CAPE * HD * 2); // expert down out
  int*   tidx  = (int*)alloc((size_t)TT * TOPK * 4);
  float* twv   = (float*)alloc((size_t)TT * TOPK * 4);
  int*   ridx  = (int*)alloc((size_t)TT * TOPK * 4);
  int*   torow = (int*)alloc((size_t)NE * CAPE * 4);
  int*   cnts  = (int*)alloc(64);
  u16* sgb = gbuf;  // shared reuse after routed FFN consumed gbuf/ubuf
  u16* sub = ubuf;

  if ((size_t)(p - base) > ws_size) {  // diagnosable failure instead of corruption
    k_sentinel<<<dim3((out_size + 255) / 256), dim3(256), 0, stream>>>(out, out_size);
    return;
  }

  dim3 b256(256), b64(64);

  k_cvt<<<dim3((TT * HD) / (8 * 256)), b256, 0, stream>>>(x, xb);
  k_gate<<<dim3(TT), b64, 0, stream>>>(x, gate_w, gate_b, tidx, twv);
  k_count_pos<<<dim3(NE), b256, 0, stream>>>(tidx, ridx, torow, cnts);

  // ---- routed experts ----
  k_transpose_cvt<<<dim3(HD / 64, ID / 64, NE), b256, 0, stream>>>(
      w_gate, wT, HD, ID, (long)HD * ID, (long)ID * HD);
  k_gemm_bt<false><<<dim3(CAPE / 128, ID / 128, NE), b256, 0, stream>>>(
      xb, wT, gbuf, torow, cnts, 0, ID, HD, HD, ID, (long)ID * HD, CAPE);
  k_transpose_cvt<<<dim3(HD / 64, ID / 64, NE), b256, 0, stream>>>(
      w_up, wT, HD, ID, (long)HD * ID, (long)ID * HD);
  k_gemm_bt<false><<<dim3(CAPE / 128, ID / 128, NE), b256, 0, stream>>>(
      xb, wT, ubuf, torow, cnts, 0, ID, HD, HD, ID, (long)ID * HD, CAPE);
  k_silu_mul<<<dim3((NE * CAPE * ID) / (8 * 256)), b256, 0, stream>>>(gbuf, ubuf, gbuf);
  k_transpose_cvt<<<dim3(ID / 64, HD / 64, NE), b256, 0, stream>>>(
      w_down, wT, ID, HD, (long)ID * HD, (long)HD * ID);
  k_gemm_bt<false><<<dim3(CAPE / 128, HD / 128, NE), b256, 0, stream>>>(
      gbuf, wT, dbuf, nullptr, cnts, 0, HD, ID, ID, HD, (long)HD * ID, CAPE);

  // ---- shared experts ----
  k_transpose_cvt<<<dim3(HD / 64, SHD / 64, 1), b256, 0, stream>>>(ws_gate, swT, HD, SHD, 0, 0);
  k_gemm_bt<false><<<dim3(TT / 128, SHD / 128, 1), b256, 0, stream>>>(
      xb, swT, sgb, nullptr, nullptr, TT, SHD, HD, HD, SHD, 0, 0);
  k_transpose_cvt<<<dim3(HD / 64, SHD / 64, 1), b256, 0, stream>>>(ws_up, swT, HD, SHD, 0, 0);
  k_gemm_bt<false><<<dim3(TT / 128, SHD / 128, 1), b256, 0, stream>>>(
      xb, swT, sub, nullptr, nullptr, TT, SHD, HD, HD, SHD, 0, 0);
  k_silu_mul<<<dim3((TT * SHD) / (8 * 256)), b256, 0, stream>>>(sgb, sub, sgb);
  k_transpose_cvt<<<dim3(SHD / 64, HD / 64, 1), b256, 0, stream>>>(ws_down, swT, SHD, HD, 0, 0);
  k_gemm_bt<true><<<dim3(TT / 128, HD / 128, 1), b256, 0, stream>>>(
      sgb, swT, out, nullptr, nullptr, TT, HD, SHD, SHD, HD, 0, 0);

  // ---- combine routed into out ----
  k_combine<<<dim3(TT), b256, 0, stream>>>(dbuf, ridx, twv, out);
}

// Round 2
// 923.840 us; speedup vs baseline: 1.1415x; 1.1415x over previous
//
#include <hip/hip_runtime.h>

typedef unsigned short u16;
typedef u16  u16x8 __attribute__((ext_vector_type(8)));
typedef u16  u16x4 __attribute__((ext_vector_type(4)));
typedef short s16x8 __attribute__((ext_vector_type(8)));
typedef float f32x4 __attribute__((ext_vector_type(4)));

static constexpr int TT   = 2048;   // tokens (B*S)
static constexpr int HD   = 2048;   // hidden
static constexpr int ID   = 1408;   // expert intermediate
static constexpr int NE   = 16;     // experts
static constexpr int TOPK = 6;
static constexpr int CAPE = 1536;   // capacity
static constexpr int SHD  = 2816;   // shared intermediate (2*I)
static constexpr float RSF_ = 2.5f;

__device__ __forceinline__ u16 f2b(float f) {
  unsigned int u = __builtin_bit_cast(unsigned int, f);
  unsigned int r = (u + 0x7FFFu + ((u >> 16) & 1u)) >> 16;
  return (u16)r;
}
__device__ __forceinline__ float b2f(u16 u) {
  unsigned int v = ((unsigned int)u) << 16;
  return __builtin_bit_cast(float, v);
}

// ---------------- x fp32 -> bf16 ----------------
__global__ __launch_bounds__(256) void k_cvt(const float* __restrict__ in, u16* __restrict__ out) {
  size_t i = (size_t)blockIdx.x * 256 + threadIdx.x;
  const float4* p = (const float4*)in;
  float4 v0 = p[i * 2], v1 = p[i * 2 + 1];
  u16x8 o = { f2b(v0.x), f2b(v0.y), f2b(v0.z), f2b(v0.w),
              f2b(v1.x), f2b(v1.y), f2b(v1.z), f2b(v1.w) };
  *(u16x8*)(out + i * 8) = o;
}

// ---------------- fused gate: coalesced fp32 logits + noaux_tc top-k ----------------
// grid = TT/8 blocks x 256 threads. Thread (i=t>>5 token, e=t&15 expert,
// kh=(t>>4)&1 K-half) computes a float4 partial dot; shfl_down(16) merges
// halves; 8 threads/block then run the serial group-limited top-k from LDS.
__global__ __launch_bounds__(256) void k_gate2(const float* __restrict__ x,
    const float* __restrict__ gw, const float* __restrict__ gb,
    int* __restrict__ topk_idx, float* __restrict__ topk_w) {
  const int t = threadIdx.x;
  const int tok0 = blockIdx.x * 8;
  const int i  = t >> 5;
  const int sub = t & 31;
  const int e  = sub & 15;
  const int kh = sub >> 4;
  const float4* xr = (const float4*)(x + (size_t)(tok0 + i) * HD) + kh * (HD / 8);
  const float4* wr = (const float4*)(gw + (size_t)e * HD) + kh * (HD / 8);
  float acc = 0.f;
  #pragma unroll 8
  for (int k = 0; k < HD / 8; ++k) {
    float4 a = xr[k], b = wr[k];
    acc += a.x * b.x + a.y * b.y;
    acc += a.z * b.z + a.w * b.w;
  }
  acc += __shfl_down(acc, 16);   // kh=0 lane now has the full dot
  __shared__ float lg[8][16];
  if (sub < 16) lg[i][e] = acc;
  __syncthreads();
  if (t >= 8) return;
  const int tok = tok0 + t;
  float s[NE], sc[NE];
  #pragma unroll
  for (int ee = 0; ee < NE; ++ee) {
    s[ee]  = 1.f / (1.f + expf(-lg[t][ee]));
    sc[ee] = s[ee] + gb[ee];
  }
  float gs[4];
  #pragma unroll
  for (int g = 0; g < 4; ++g) {
    float m1 = -1e30f, m2 = -1e30f;
    #pragma unroll
    for (int j = 0; j < 4; ++j) {
      float v = sc[g * 4 + j];
      if (v > m1) { m2 = m1; m1 = v; } else if (v > m2) m2 = v;
    }
    gs[g] = m1 + m2;
  }
  int g0 = 0;
  #pragma unroll
  for (int g = 1; g < 4; ++g) if (gs[g] > gs[g0]) g0 = g;
  int g1 = -1; float g1v = -1e30f;
  #pragma unroll
  for (int g = 0; g < 4; ++g) {
    if (g == g0) continue;
    if (g1 < 0 || gs[g] > g1v) { g1 = g; g1v = gs[g]; }
  }
  float tmp[NE];
  #pragma unroll
  for (int ee = 0; ee < NE; ++ee) {
    int g = ee >> 2;
    tmp[ee] = (g == g0 || g == g1) ? sc[ee] : 0.0f;   // matches reference mask value
  }
  unsigned used = 0;
  float wsum = 0.f;
  int idxs[TOPK]; float wv[TOPK];
  #pragma unroll
  for (int k = 0; k < TOPK; ++k) {
    int best = -1; float bv = -2e30f;
    #pragma unroll
    for (int ee = 0; ee < NE; ++ee) {
      bool ok = (((used >> ee) & 1u) == 0u) && (tmp[ee] > bv);
      if (ok) { bv = tmp[ee]; best = ee; }
    }
    used |= 1u << best;
    float sv = 0.f;
    #pragma unroll
    for (int ee = 0; ee < NE; ++ee) if (ee == best) sv = s[ee];
    idxs[k] = best; wv[k] = sv; wsum += sv;
  }
  float scale = RSF_ / (wsum + 1e-20f);
  #pragma unroll
  for (int k = 0; k < TOPK; ++k) {
    topk_idx[tok * TOPK + k] = idxs[k];
    topk_w[tok * TOPK + k]   = wv[k] * scale;
  }
}

// ---------------- stable per-expert positions (matches stable sort) ----------------
__global__ __launch_bounds__(256) void k_count_pos(const int* __restrict__ topk_idx,
    int* __restrict__ rowidx, int* __restrict__ tok_of_row, int* __restrict__ counts) {
  const int e = blockIdx.x, t = threadIdx.x;
  __shared__ int pref[256];
  const int t0 = t * 8;
  int c = 0;
  for (int tt = t0; tt < t0 + 8; ++tt)
    for (int k = 0; k < TOPK; ++k) c += (topk_idx[tt * TOPK + k] == e) ? 1 : 0;
  pref[t] = c;
  __syncthreads();
  for (int off = 1; off < 256; off <<= 1) {
    int v = (t >= off) ? pref[t - off] : 0;
    __syncthreads();
    pref[t] += v;
    __syncthreads();
  }
  int run = pref[t] - c;  // exclusive prefix
  if (t == 255) counts[e] = (pref[255] < CAPE) ? pref[255] : CAPE;
  for (int tt = t0; tt < t0 + 8; ++tt)
    for (int k = 0; k < TOPK; ++k)
      if (topk_idx[tt * TOPK + k] == e) {
        if (run < CAPE) {
          rowidx[tt * TOPK + k] = e * CAPE + run;
          tok_of_row[e * CAPE + run] = tt;
        } else {
          rowidx[tt * TOPK + k] = -1;   // dropped (should not happen)
        }
        ++run;
      }
}

// ---------------- transpose + convert: fp32 [R][C] -> bf16 [C][R] ----------------
__global__ __launch_bounds__(256) void k_transpose_cvt(const float* __restrict__ in,
    u16* __restrict__ out, int R, int Cc, long zin, long zout) {
  __shared__ float tile[64][65];
  const float* src = in + (size_t)blockIdx.z * zin;
  u16* dst = out + (size_t)blockIdx.z * zout;
  const int r0 = blockIdx.x * 64, c0 = blockIdx.y * 64, t = threadIdx.x;
  #pragma unroll
  for (int i = 0; i < 4; ++i) {
    int c = t + 256 * i;
    int r = c >> 4, cg = (c & 15) << 2;
    float4 v = *(const float4*)(src + (size_t)(r0 + r) * Cc + c0 + cg);
    tile[r][cg + 0] = v.x; tile[r][cg + 1] = v.y;
    tile[r][cg + 2] = v.z; tile[r][cg + 3] = v.w;
  }
  __syncthreads();
  #pragma unroll
  for (int i = 0; i < 4; ++i) {
    int c = t + 256 * i;
    int oc = c >> 4, og = (c & 15) << 2;
    u16x4 w;
    #pragma unroll
    for (int j = 0; j < 4; ++j) w[j] = f2b(tile[og + j][oc]);
    *(u16x4*)(dst + (size_t)(c0 + oc) * R + r0 + og) = w;
  }
}

// ---------------- bf16 GEMM: C = A[M][K] * Bt[N][K]^T  (grouped via z) ----------------
template <bool C_F32>
__global__ __launch_bounds__(256) void k_gemm_bt(
    const u16* __restrict__ A, const u16* __restrict__ Bt, void* __restrict__ Cptr,
    const int* __restrict__ row_map, const int* __restrict__ counts,
    int Mfixed, int N, int K, int lda, int ldc, long bt_stride, int row_cap) {
  const int e = blockIdx.z;
  const int cnt = counts ? counts[e] : Mfixed;
  const int M_e = counts ? (cnt < row_cap ? cnt : row_cap) : Mfixed;
  const int m0 = blockIdx.x * 128;
  if (m0 >= M_e) return;
  const int n0 = blockIdx.y * 128;
  const int row_base = counts ? e * row_cap : 0;
  const u16* Bte = Bt + (size_t)e * bt_stride;

  __shared__ __align__(16) u16 As[128 * 32];
  __shared__ __align__(16) u16 Bs[128 * 32];

  const int t = threadIdx.x;
  const int l = t & 63, w = t >> 6;
  const int wm = (w >> 1) * 64, wn = (w & 1) * 64;

  const u16* aptr[2]; const u16* bptr[2];
  int lds_off[2];
  #pragma unroll
  for (int i = 0; i < 2; ++i) {
    int c = t + 256 * i;
    int row = c >> 2, kg = c & 3;
    int sw = (row ^ (row >> 2)) & 3;
    lds_off[i] = row * 64 + (((kg ^ sw) & 3) << 4);
    int rg = m0 + row; if (rg > M_e - 1) rg = M_e - 1;
    int arow = row_map ? row_map[row_base + rg] : row_base + rg;
    aptr[i] = A + (size_t)arow * lda + kg * 8;
    bptr[i] = Bte + (size_t)(n0 + row) * K + kg * 8;
  }

  f32x4 acc[4][4];
  #pragma unroll
  for (int m = 0; m < 4; ++m)
    #pragma unroll
    for (int n = 0; n < 4; ++n) acc[m][n] = f32x4{0.f, 0.f, 0.f, 0.f};

  int aoff[4], boff[4];
  {
    int l15 = l & 15, g = l >> 4;
    int sw = (l15 ^ (l15 >> 2)) & 3;
    #pragma unroll
    for (int i = 0; i < 4; ++i) {
      int rA = wm + i * 16 + l15;
      int rB = wn + i * 16 + l15;
      aoff[i] = rA * 64 + (((g ^ sw) & 3) << 4);
      boff[i] = rB * 64 + (((g ^ sw) & 3) << 4);
    }
  }

  const int nk = K >> 5;
  for (int ks = 0; ks < nk; ++ks) {
    u16x8 av[2], bv[2];
    #pragma unroll
    for (int i = 0; i < 2; ++i) {
      av[i] = *(const u16x8*)aptr[i]; aptr[i] += 32;
      bv[i] = *(const u16x8*)bptr[i]; bptr[i] += 32;
    }
    __syncthreads();
    #pragma unroll
    for (int i = 0; i < 2; ++i) {
      *(u16x8*)((char*)As + lds_off[i]) = av[i];
      *(u16x8*)((char*)Bs + lds_off[i]) = bv[i];
    }
    __syncthreads();
    s16x8 af[4], bfr[4];
    #pragma unroll
    for (int i = 0; i < 4; ++i) {
      af[i]  = __builtin_bit_cast(s16x8, *(const u16x8*)((const char*)As + aoff[i]));
      bfr[i] = __builtin_bit_cast(s16x8, *(const u16x8*)((const char*)Bs + boff[i]));
    }
    #pragma unroll
    for (int m = 0; m < 4; ++m)
      #pragma unroll
      for (int n = 0; n < 4; ++n)
        acc[m][n] = __builtin_amdgcn_mfma_f32_16x16x32_bf16(af[m], bfr[n], acc[m][n], 0, 0, 0);
  }

  const int cl = l & 15, rw = (l >> 4) * 4;
  #pragma unroll
  for (int m = 0; m < 4; ++m) {
    #pragma unroll
    for (int n = 0; n < 4; ++n) {
      f32x4 v = acc[m][n];
      int gr0 = m0 + wm + m * 16 + rw;
      int gc  = n0 + wn + n * 16 + cl;
      #pragma unroll
      for (int j = 0; j < 4; ++j) {
        int r = gr0 + j;
        if (r < M_e) {
          size_t ci = (size_t)(row_base + r) * ldc + gc;
          if (C_F32) ((float*)Cptr)[ci] = v[j];
          else       ((u16*)Cptr)[ci]   = f2b(v[j]);
        }
      }
    }
  }
}

// ---------------- silu(g)*u, elementwise, in bf16 (may alias o==g) ----------------
__global__ __launch_bounds__(256) void k_silu_mul(const u16* __restrict__ g,
    const u16* __restrict__ u, u16* __restrict__ o) {
  size_t i = (size_t)blockIdx.x * 256 + threadIdx.x;
  u16x8 gv = *(const u16x8*)(g + i * 8);
  u16x8 uv = *(const u16x8*)(u + i * 8);
  u16x8 ov;
  #pragma unroll
  for (int j = 0; j < 8; ++j) {
    float gf = b2f(gv[j]), uf = b2f(uv[j]);
    float sf = gf / (1.f + __expf(-gf));
    ov[j] = f2b(sf * uf);
  }
  *(u16x8*)(o + i * 8) = ov;
}

// ---------------- combine: out[t] += sum_k w * down[row(t,k)] ----------------
__global__ __launch_bounds__(256) void k_combine(const u16* __restrict__ down,
    const int* __restrict__ rowidx, const float* __restrict__ tw,
    float* __restrict__ out) {
  const int t = blockIdx.x, l = threadIdx.x;
  __shared__ int rid[TOPK];
  __shared__ float wk[TOPK];
  if (l < TOPK) { rid[l] = rowidx[t * TOPK + l]; wk[l] = tw[t * TOPK + l]; }
  __syncthreads();
  const int h0 = l * 8;
  float* op = out + (size_t)t * HD + h0;
  float4 o0 = *(float4*)op, o1 = *(float4*)(op + 4);
  float a[8] = { o0.x, o0.y, o0.z, o0.w, o1.x, o1.y, o1.z, o1.w };
  #pragma unroll
  for (int k = 0; k < TOPK; ++k) {
    int r = rid[k];
    if (r < 0) continue;
    float wkk = wk[k];
    u16x8 v = *(const u16x8*)(down + (size_t)r * HD + h0);
    #pragma unroll
    for (int j = 0; j < 8; ++j) a[j] += wkk * b2f(v[j]);
  }
  o0 = make_float4(a[0], a[1], a[2], a[3]);
  o1 = make_float4(a[4], a[5], a[6], a[7]);
  *(float4*)op = o0;
  *(float4*)(op + 4) = o1;
}

__global__ __launch_bounds__(256) void k_sentinel(float* o, int n) {
  int i = blockIdx.x * 256 + threadIdx.x;
  if (i < n) o[i] = 12345.0f;
}

extern "C" void kernel_launch(void* const* d_in, const int* in_sizes, int n_in,
                              void* d_out, int out_size, void* d_ws, size_t ws_size,
                              hipStream_t stream) {
  const float* x       = (const float*)d_in[0];
  const float* gate_w  = (const float*)d_in[1];
  const float* gate_b  = (const float*)d_in[2];
  const float* w_gate  = (const float*)d_in[3];
  const float* w_up    = (const float*)d_in[4];
  const float* w_down  = (const float*)d_in[5];
  const float* ws_gate = (const float*)d_in[6];
  const float* ws_up   = (const float*)d_in[7];
  const float* ws_down = (const float*)d_in[8];
  float* out = (float*)d_out;

  char* base = (char*)d_ws;
  char* p = base;
  auto alloc = [&](size_t bytes) -> char* {
    char* r = p;
    p += (bytes + 255) & ~(size_t)255;
    return r;
  };
  u16* wT    = (u16*)alloc((size_t)NE * ID * HD * 2);   // routed weight^T (reused x3)
  u16* swT   = (u16*)alloc((size_t)SHD * HD * 2);       // shared weight^T (reused x3)
  u16* xb    = (u16*)alloc((size_t)TT * HD * 2);        // x in bf16
  u16* gbuf  = (u16*)alloc((size_t)NE * CAPE * ID * 2); // g -> act ; later sg
  u16* ubuf  = (u16*)alloc((size_t)NE * CAPE * ID * 2); // u        ; later su
  u16* dbuf  = (u16*)alloc((size_t)NE * CAPE * HD * 2); // expert down out
  int*   tidx  = (int*)alloc((size_t)TT * TOPK * 4);
  float* twv   = (float*)alloc((size_t)TT * TOPK * 4);
  int*   ridx  = (int*)alloc((size_t)TT * TOPK * 4);
  int*   torow = (int*)alloc((size_t)NE * CAPE * 4);
  int*   cnts  = (int*)alloc(64);
  u16* sgb = gbuf;
  u16* sub = ubuf;

  if ((size_t)(p - base) > ws_size) {
    k_sentinel<<<dim3((out_size + 255) / 256), dim3(256), 0, stream>>>(out, out_size);
    return;
  }

  dim3 b256(256);

  k_cvt<<<dim3((TT * HD) / (8 * 256)), b256, 0, stream>>>(x, xb);
  k_gate2<<<dim3(TT / 8), b256, 0, stream>>>(x, gate_w, gate_b, tidx, twv);
  k_count_pos<<<dim3(NE), b256, 0, stream>>>(tidx, ridx, torow, cnts);

  // ---- routed experts ----
  k_transpose_cvt<<<dim3(HD / 64, ID / 64, NE), b256, 0, stream>>>(
      w_gate, wT, HD, ID, (long)HD * ID, (long)ID * HD);
  k_gemm_bt<false><<<dim3(CAPE / 128, ID / 128, NE), b256, 0, stream>>>(
      xb, wT, gbuf, torow, cnts, 0, ID, HD, HD, ID, (long)ID * HD, CAPE);
  k_transpose_cvt<<<dim3(HD / 64, ID / 64, NE), b256, 0, stream>>>(
      w_up, wT, HD, ID, (long)HD * ID, (long)ID * HD);
  k_gemm_bt<false><<<dim3(CAPE / 128, ID / 128, NE), b256, 0, stream>>>(
      xb, wT, ubuf, torow, cnts, 0, ID, HD, HD, ID, (long)ID * HD, CAPE);
  k_silu_mul<<<dim3((NE * CAPE * ID) / (8 * 256)), b256, 0, stream>>>(gbuf, ubuf, gbuf);
  k_transpose_cvt<<<dim3(ID / 64, HD / 64, NE), b256, 0, stream>>>(
      w_down, wT, ID, HD, (long)ID * HD, (long)HD * ID);
  k_gemm_bt<false><<<dim3(CAPE / 128, HD / 128, NE), b256, 0, stream>>>(
      gbuf, wT, dbuf, nullptr, cnts, 0, HD, ID, ID, HD, (long)HD * ID, CAPE);

  // ---- shared experts ----
  k_transpose_cvt<<<dim3(HD / 64, SHD / 64, 1), b256, 0, stream>>>(ws_gate, swT, HD, SHD, 0, 0);
  k_gemm_bt<false><<<dim3(TT / 128, SHD / 128, 1), b256, 0, stream>>>(
      xb, swT, sgb, nullptr, nullptr, TT, SHD, HD, HD, SHD, 0, 0);
  k_transpose_cvt<<<dim3(HD / 64, SHD / 64, 1), b256, 0, stream>>>(ws_up, swT, HD, SHD, 0, 0);
  k_gemm_bt<false><<<dim3(TT / 128, SHD / 128, 1), b256, 0, stream>>>(
      xb, swT, sub, nullptr, nullptr, TT, SHD, HD, HD, SHD, 0, 0);
  k_silu_mul<<<dim3((TT * SHD) / (8 * 256)), b256, 0, stream>>>(sgb, sub, sgb);
  k_transpose_cvt<<<dim3(SHD / 64, HD / 64, 1), b256, 0, stream>>>(ws_down, swT, SHD, HD, 0, 0);
  k_gemm_bt<true><<<dim3(TT / 128, HD / 128, 1), b256, 0, stream>>>(
      sgb, swT, out, nullptr, nullptr, TT, HD, SHD, SHD, HD, 0, 0);

  // ---- combine routed into out ----
  k_combine<<<dim3(TT), b256, 0, stream>>>(dbuf, ridx, twv, out);
}